// Round 1
// baseline (2890.848 us; speedup 1.0000x reference)
//
#include <hip/hip_runtime.h>

#define HD 8
#define ALPHA_LRELU 0.2f

// ---------------- GEMM: H[m,o] = sum_k X[m,k] * W[o,k]  (both row-major, K=N=256)
__global__ __launch_bounds__(256) void gemm_xwt(
    const float* __restrict__ X, const float* __restrict__ W,
    float* __restrict__ Hout, int M)
{
    // 64x64 tile, BK=16, 256 threads, 4x4 micro-tile, transposed LDS (stride 68 keeps
    // float4 alignment: 68*4=272 bytes = 17*16; 2-way bank aliasing only = free)
    __shared__ __align__(16) float Xs[16][68];
    __shared__ __align__(16) float Ws[16][68];
    const int tid = threadIdx.x;
    const int bm = blockIdx.x * 64;
    const int bn = blockIdx.y * 64;
    const int tx = tid & 15;
    const int ty = tid >> 4;
    const int lrow = tid >> 2;        // 0..63
    const int lk4  = (tid & 3) << 2;  // 0,4,8,12
    float acc[4][4] = {};
    for (int kb = 0; kb < 256; kb += 16) {
        float4 xv = make_float4(0.f, 0.f, 0.f, 0.f);
        const int grow = bm + lrow;
        if (grow < M) xv = *(const float4*)(X + (size_t)grow * 256 + kb + lk4);
        const float4 wv = *(const float4*)(W + (size_t)(bn + lrow) * 256 + kb + lk4);
        __syncthreads();
        Xs[lk4 + 0][lrow] = xv.x; Xs[lk4 + 1][lrow] = xv.y;
        Xs[lk4 + 2][lrow] = xv.z; Xs[lk4 + 3][lrow] = xv.w;
        Ws[lk4 + 0][lrow] = wv.x; Ws[lk4 + 1][lrow] = wv.y;
        Ws[lk4 + 2][lrow] = wv.z; Ws[lk4 + 3][lrow] = wv.w;
        __syncthreads();
        #pragma unroll
        for (int kk = 0; kk < 16; ++kk) {
            const float4 av = *(const float4*)(&Xs[kk][ty << 2]);
            const float4 bv = *(const float4*)(&Ws[kk][tx << 2]);
            const float a_[4] = {av.x, av.y, av.z, av.w};
            const float b_[4] = {bv.x, bv.y, bv.z, bv.w};
            #pragma unroll
            for (int i = 0; i < 4; ++i)
                #pragma unroll
                for (int j = 0; j < 4; ++j)
                    acc[i][j] = fmaf(a_[i], b_[j], acc[i][j]);
        }
    }
    #pragma unroll
    for (int i = 0; i < 4; ++i) {
        const int grow = bm + (ty << 2) + i;
        if (grow < M) {
            float4 o = make_float4(acc[i][0], acc[i][1], acc[i][2], acc[i][3]);
            *(float4*)(Hout + (size_t)grow * 256 + bn + (tx << 2)) = o;
        }
    }
}

// ---------------- alpha_src[n,h] = <h[n,h,:], a[0:32]>, alpha_tgt = <h[n,h,:], a[32:64]>
__global__ __launch_bounds__(256) void alpha_kernel(
    const float* __restrict__ Hf, const float* __restrict__ a,
    float* __restrict__ asrc, float* __restrict__ atgt, int NH)
{
    const int idx = blockIdx.x * 256 + threadIdx.x;
    if (idx >= NH) return;
    const float4* hp = (const float4*)(Hf + (size_t)idx * 32);
    float s1 = 0.f, s2 = 0.f;
    #pragma unroll
    for (int q = 0; q < 8; ++q) {
        const float4 v  = hp[q];
        const float4 c1 = *(const float4*)(a + q * 4);
        const float4 c2 = *(const float4*)(a + 32 + q * 4);
        s1 += v.x * c1.x + v.y * c1.y + v.z * c1.z + v.w * c1.w;
        s2 += v.x * c2.x + v.y * c2.y + v.z * c2.z + v.w * c2.w;
    }
    asrc[idx] = s1;
    atgt[idx] = s2;
}

// ---------------- segment max over src: rowmax[n,h] = max(max_e score, 0)
// rowmax buffer pre-zeroed; only positive scores matter, and non-negative IEEE
// floats order as unsigned ints -> atomicMax on the bit pattern.
__global__ __launch_bounds__(256) void edge_max_kernel(
    const int* __restrict__ src, const int* __restrict__ tgt,
    const float* __restrict__ asrc, const float* __restrict__ atgt,
    unsigned int* __restrict__ rowmax_u, int E_)
{
    const int idx = blockIdx.x * 256 + threadIdx.x;
    if (idx >= E_ * HD) return;
    const int e = idx >> 3, hd = idx & 7;
    const int s = src[e], t = tgt[e];
    float sc = asrc[s * HD + hd] + atgt[t * HD + hd];
    sc = sc > 0.f ? sc : ALPHA_LRELU * sc;
    if (sc > 0.f) atomicMax(&rowmax_u[s * HD + hd], __float_as_uint(sc));
}

// ---------------- segment sum of exp(score - rowmax[src]); also degree count
__global__ __launch_bounds__(256) void edge_sum_kernel(
    const int* __restrict__ src, const int* __restrict__ tgt,
    const float* __restrict__ asrc, const float* __restrict__ atgt,
    const float* __restrict__ rowmax, float* __restrict__ sumbuf,
    int* __restrict__ deg, int E_)
{
    const int idx = blockIdx.x * 256 + threadIdx.x;
    if (idx >= E_ * HD) return;
    const int e = idx >> 3, hd = idx & 7;
    const int s = src[e], t = tgt[e];
    float sc = asrc[s * HD + hd] + atgt[t * HD + hd];
    sc = sc > 0.f ? sc : ALPHA_LRELU * sc;
    const float ex = expf(sc - rowmax[s * HD + hd]);
    unsafeAtomicAdd(&sumbuf[s * HD + hd], ex);
    if (hd == 0) atomicAdd(&deg[s], 1);
}

// ---------------- denom[n,h] = sum + (N - deg[n]) * exp(-rowmax); store reciprocal
__global__ __launch_bounds__(256) void denom_kernel(
    const float* __restrict__ rowmax, const float* __restrict__ sumbuf,
    const int* __restrict__ deg, float* __restrict__ invden, int N_)
{
    const int idx = blockIdx.x * 256 + threadIdx.x;
    if (idx >= N_ * HD) return;
    const int n = idx >> 3;
    const float rm = rowmax[idx];
    const float dnm = sumbuf[idx] + (float)(N_ - deg[n]) * expf(-rm);
    invden[idx] = 1.0f / dnm;
}

// ---------------- aggregation: one wave per edge, 4 floats/lane
__global__ __launch_bounds__(256) void agg_kernel(
    const int* __restrict__ src, const int* __restrict__ tgt,
    const float* __restrict__ asrc, const float* __restrict__ atgt,
    const float* __restrict__ rowmax, const float* __restrict__ invden,
    const float* __restrict__ Hf, float* __restrict__ out, int E_)
{
    const int gid = blockIdx.x * 256 + threadIdx.x;
    const int e = gid >> 6;
    if (e >= E_) return;
    const int lane = gid & 63;
    const int s = src[e], t = tgt[e];
    const int hd = lane >> 3;  // (lane*4)/32
    float sc = asrc[s * HD + hd] + atgt[t * HD + hd];
    sc = sc > 0.f ? sc : ALPHA_LRELU * sc;
    const float attn = expf(sc - rowmax[s * HD + hd]) * invden[s * HD + hd];
    const float4 hv = *(const float4*)(Hf + (size_t)t * 256 + (lane << 2));
    float* op = out + (size_t)s * 256 + (lane << 2);
    unsafeAtomicAdd(op + 0, attn * hv.x);
    unsafeAtomicAdd(op + 1, attn * hv.y);
    unsafeAtomicAdd(op + 2, attn * hv.z);
    unsafeAtomicAdd(op + 3, attn * hv.w);
}

// ---------------- isolated nodes keep h
__global__ __launch_bounds__(256) void fix_kernel(
    const int* __restrict__ deg, const float* __restrict__ Hf,
    float* __restrict__ out, int N_)
{
    const int idx = blockIdx.x * 256 + threadIdx.x;  // over N*64 float4s
    if (idx >= N_ * 64) return;
    const int n = idx >> 6;
    if (deg[n] == 0)
        *(float4*)(out + (size_t)idx * 4) = *(const float4*)(Hf + (size_t)idx * 4);
}

extern "C" void kernel_launch(void* const* d_in, const int* in_sizes, int n_in,
                              void* d_out, int out_size, void* d_ws, size_t ws_size,
                              hipStream_t stream)
{
    const float* X  = (const float*)d_in[0];
    const int*   ei = (const int*)d_in[1];
    const float* W  = (const float*)d_in[2];
    const float* a  = (const float*)d_in[3];
    float* out = (float*)d_out;

    const int N_ = in_sizes[0] / 256;  // 50000
    const int E_ = in_sizes[1] / 2;    // 800000
    const int* src = ei;
    const int* tgt = ei + E_;

    // workspace layout (floats): h | asrc | atgt | rowmax | sumbuf | invden | deg(int)
    float* Hf     = (float*)d_ws;                 // N*256
    float* asrc   = Hf     + (size_t)N_ * 256;    // N*8
    float* atgt   = asrc   + (size_t)N_ * HD;
    float* rowmax = atgt   + (size_t)N_ * HD;
    float* sumbuf = rowmax + (size_t)N_ * HD;
    float* invden = sumbuf + (size_t)N_ * HD;
    int*   deg    = (int*)(invden + (size_t)N_ * HD);

    // per-call zero-init (harness poisons but does not re-poison between replays)
    hipMemsetAsync(rowmax, 0, (size_t)N_ * HD * 2 * sizeof(float), stream);  // rowmax+sumbuf
    hipMemsetAsync(deg, 0, (size_t)N_ * sizeof(int), stream);
    hipMemsetAsync(out, 0, (size_t)N_ * 256 * sizeof(float), stream);

    dim3 ggrid((N_ + 63) / 64, 4);
    gemm_xwt<<<ggrid, 256, 0, stream>>>(X, W, Hf, N_);
    alpha_kernel<<<(N_ * HD + 255) / 256, 256, 0, stream>>>(Hf, a, asrc, atgt, N_ * HD);
    edge_max_kernel<<<(E_ * HD + 255) / 256, 256, 0, stream>>>(
        src, tgt, asrc, atgt, (unsigned int*)rowmax, E_);
    edge_sum_kernel<<<(E_ * HD + 255) / 256, 256, 0, stream>>>(
        src, tgt, asrc, atgt, rowmax, sumbuf, deg, E_);
    denom_kernel<<<(N_ * HD + 255) / 256, 256, 0, stream>>>(rowmax, sumbuf, deg, invden, N_);
    const int agg_blocks = (int)(((size_t)E_ * 64 + 255) / 256);
    agg_kernel<<<agg_blocks, 256, 0, stream>>>(
        src, tgt, asrc, atgt, rowmax, invden, Hf, out, E_);
    fix_kernel<<<(N_ * 64 + 255) / 256, 256, 0, stream>>>(deg, Hf, out, N_);
}

// Round 2
// 412.463 us; speedup vs baseline: 7.0087x; 7.0087x over previous
//
#include <hip/hip_runtime.h>

#define HD 8
#define ALPHA_LRELU 0.2f

// ---------------- GEMM: H[m,o] = sum_k X[m,k] * W[o,k]  (both row-major, K=N=256)
__global__ __launch_bounds__(256) void gemm_xwt(
    const float* __restrict__ X, const float* __restrict__ W,
    float* __restrict__ Hout, int M)
{
    __shared__ __align__(16) float Xs[16][68];
    __shared__ __align__(16) float Ws[16][68];
    const int tid = threadIdx.x;
    const int bm = blockIdx.x * 64;
    const int bn = blockIdx.y * 64;
    const int tx = tid & 15;
    const int ty = tid >> 4;
    const int lrow = tid >> 2;        // 0..63
    const int lk4  = (tid & 3) << 2;  // 0,4,8,12
    float acc[4][4] = {};
    for (int kb = 0; kb < 256; kb += 16) {
        float4 xv = make_float4(0.f, 0.f, 0.f, 0.f);
        const int grow = bm + lrow;
        if (grow < M) xv = *(const float4*)(X + (size_t)grow * 256 + kb + lk4);
        const float4 wv = *(const float4*)(W + (size_t)(bn + lrow) * 256 + kb + lk4);
        __syncthreads();
        Xs[lk4 + 0][lrow] = xv.x; Xs[lk4 + 1][lrow] = xv.y;
        Xs[lk4 + 2][lrow] = xv.z; Xs[lk4 + 3][lrow] = xv.w;
        Ws[lk4 + 0][lrow] = wv.x; Ws[lk4 + 1][lrow] = wv.y;
        Ws[lk4 + 2][lrow] = wv.z; Ws[lk4 + 3][lrow] = wv.w;
        __syncthreads();
        #pragma unroll
        for (int kk = 0; kk < 16; ++kk) {
            const float4 av = *(const float4*)(&Xs[kk][ty << 2]);
            const float4 bv = *(const float4*)(&Ws[kk][tx << 2]);
            const float a_[4] = {av.x, av.y, av.z, av.w};
            const float b_[4] = {bv.x, bv.y, bv.z, bv.w};
            #pragma unroll
            for (int i = 0; i < 4; ++i)
                #pragma unroll
                for (int j = 0; j < 4; ++j)
                    acc[i][j] = fmaf(a_[i], b_[j], acc[i][j]);
        }
    }
    #pragma unroll
    for (int i = 0; i < 4; ++i) {
        const int grow = bm + (ty << 2) + i;
        if (grow < M) {
            float4 o = make_float4(acc[i][0], acc[i][1], acc[i][2], acc[i][3]);
            *(float4*)(Hout + (size_t)grow * 256 + bn + (tx << 2)) = o;
        }
    }
}

// ---------------- alpha dot products
__global__ __launch_bounds__(256) void alpha_kernel(
    const float* __restrict__ Hf, const float* __restrict__ a,
    float* __restrict__ asrc, float* __restrict__ atgt, int NH)
{
    const int idx = blockIdx.x * 256 + threadIdx.x;
    if (idx >= NH) return;
    const float4* hp = (const float4*)(Hf + (size_t)idx * 32);
    float s1 = 0.f, s2 = 0.f;
    #pragma unroll
    for (int q = 0; q < 8; ++q) {
        const float4 v  = hp[q];
        const float4 c1 = *(const float4*)(a + q * 4);
        const float4 c2 = *(const float4*)(a + 32 + q * 4);
        s1 += v.x * c1.x + v.y * c1.y + v.z * c1.z + v.w * c1.w;
        s2 += v.x * c2.x + v.y * c2.y + v.z * c2.z + v.w * c2.w;
    }
    asrc[idx] = s1;
    atgt[idx] = s2;
}

// ---------------- histogram of src -> deg
__global__ __launch_bounds__(256) void hist_kernel(
    const int* __restrict__ src, int* __restrict__ deg, int E_)
{
    const int e = blockIdx.x * 256 + threadIdx.x;
    if (e < E_) atomicAdd(&deg[src[e]], 1);
}

// ---------------- 3-kernel exclusive scan of deg -> rowptr
__global__ __launch_bounds__(256) void scan_block(
    const int* __restrict__ deg, int* __restrict__ rowptr,
    int* __restrict__ bsums, int N_)
{
    __shared__ int sm[256];
    const int i = blockIdx.x * 256 + threadIdx.x;
    const int v = (i < N_) ? deg[i] : 0;
    sm[threadIdx.x] = v;
    __syncthreads();
    #pragma unroll
    for (int off = 1; off < 256; off <<= 1) {
        int t = 0;
        if ((int)threadIdx.x >= off) t = sm[threadIdx.x - off];
        __syncthreads();
        sm[threadIdx.x] += t;
        __syncthreads();
    }
    if (i < N_) rowptr[i] = sm[threadIdx.x] - v;   // exclusive
    if (threadIdx.x == 255) bsums[blockIdx.x] = sm[255];
}

__global__ __launch_bounds__(256) void scan_sums(int* __restrict__ bsums, int nb)
{
    __shared__ int sm[256];
    const int v = ((int)threadIdx.x < nb) ? bsums[threadIdx.x] : 0;
    sm[threadIdx.x] = v;
    __syncthreads();
    #pragma unroll
    for (int off = 1; off < 256; off <<= 1) {
        int t = 0;
        if ((int)threadIdx.x >= off) t = sm[threadIdx.x - off];
        __syncthreads();
        sm[threadIdx.x] += t;
        __syncthreads();
    }
    if ((int)threadIdx.x < nb) bsums[threadIdx.x] = sm[threadIdx.x] - v;  // exclusive
}

__global__ __launch_bounds__(256) void scan_add(
    int* __restrict__ rowptr, const int* __restrict__ bsums, int N_)
{
    const int i = blockIdx.x * 256 + threadIdx.x;
    if (i < N_) rowptr[i] += bsums[blockIdx.x];
}

// ---------------- scatter tgt into CSR order
__global__ __launch_bounds__(256) void scatter_kernel(
    const int* __restrict__ src, const int* __restrict__ tgt,
    const int* __restrict__ rowptr, int* __restrict__ cursor,
    int* __restrict__ csr_tgt, int E_)
{
    const int e = blockIdx.x * 256 + threadIdx.x;
    if (e >= E_) return;
    const int s = src[e];
    const int pos = atomicAdd(&cursor[s], 1);
    csr_tgt[rowptr[s] + pos] = tgt[e];
}

// ---------------- segment max over src (uint-bit atomicMax; only sc>0 matters)
__global__ __launch_bounds__(256) void edge_max_kernel(
    const int* __restrict__ src, const int* __restrict__ tgt,
    const float* __restrict__ asrc, const float* __restrict__ atgt,
    unsigned int* __restrict__ rowmax_u, int E_)
{
    const int idx = blockIdx.x * 256 + threadIdx.x;
    if (idx >= E_ * HD) return;
    const int e = idx >> 3, hd = idx & 7;
    const int s = src[e], t = tgt[e];
    float sc = asrc[s * HD + hd] + atgt[t * HD + hd];
    sc = sc > 0.f ? sc : ALPHA_LRELU * sc;
    if (sc > 0.f) atomicMax(&rowmax_u[s * HD + hd], __float_as_uint(sc));
}

// ---------------- segment sum of exp(score - rowmax[src])
__global__ __launch_bounds__(256) void edge_sum_kernel(
    const int* __restrict__ src, const int* __restrict__ tgt,
    const float* __restrict__ asrc, const float* __restrict__ atgt,
    const float* __restrict__ rowmax, float* __restrict__ sumbuf, int E_)
{
    const int idx = blockIdx.x * 256 + threadIdx.x;
    if (idx >= E_ * HD) return;
    const int e = idx >> 3, hd = idx & 7;
    const int s = src[e], t = tgt[e];
    float sc = asrc[s * HD + hd] + atgt[t * HD + hd];
    sc = sc > 0.f ? sc : ALPHA_LRELU * sc;
    const float ex = expf(sc - rowmax[s * HD + hd]);
    unsafeAtomicAdd(&sumbuf[s * HD + hd], ex);
}

// ---------------- denom -> reciprocal
__global__ __launch_bounds__(256) void denom_kernel(
    const float* __restrict__ rowmax, const float* __restrict__ sumbuf,
    const int* __restrict__ deg, float* __restrict__ invden, int N_)
{
    const int idx = blockIdx.x * 256 + threadIdx.x;
    if (idx >= N_ * HD) return;
    const int n = idx >> 3;
    const float rm = rowmax[idx];
    const float dnm = sumbuf[idx] + (float)(N_ - deg[n]) * expf(-rm);
    invden[idx] = 1.0f / dnm;
}

// ---------------- aggregation: one wave per node, accumulate in registers, no atomics
__global__ __launch_bounds__(256) void node_agg(
    const int* __restrict__ rowptr, const int* __restrict__ deg,
    const int* __restrict__ csr_tgt,
    const float* __restrict__ asrc, const float* __restrict__ atgt,
    const float* __restrict__ rowmax, const float* __restrict__ invden,
    const float* __restrict__ Hf, float* __restrict__ out, int N_)
{
    const int s = (blockIdx.x * 256 + threadIdx.x) >> 6;   // node = global wave id
    if (s >= N_) return;
    const int lane = threadIdx.x & 63;
    const int d = deg[s];
    if (d == 0) {
        // isolated node keeps h
        *(float4*)(out + (size_t)s * 256 + (lane << 2)) =
            *(const float4*)(Hf + (size_t)s * 256 + (lane << 2));
        return;
    }
    const int hd = lane >> 3;                 // head for this lane's 4 dims
    const float as  = asrc[s * HD + hd];
    const float rm  = rowmax[s * HD + hd];
    const float inv = invden[s * HD + hd];
    const int beg = rowptr[s];
    float4 acc = make_float4(0.f, 0.f, 0.f, 0.f);
    for (int i = 0; i < d; ++i) {
        const int t = csr_tgt[beg + i];
        float sc = as + atgt[t * HD + hd];
        sc = sc > 0.f ? sc : ALPHA_LRELU * sc;
        const float attn = expf(sc - rm) * inv;
        const float4 hv = *(const float4*)(Hf + (size_t)t * 256 + (lane << 2));
        acc.x = fmaf(attn, hv.x, acc.x);
        acc.y = fmaf(attn, hv.y, acc.y);
        acc.z = fmaf(attn, hv.z, acc.z);
        acc.w = fmaf(attn, hv.w, acc.w);
    }
    *(float4*)(out + (size_t)s * 256 + (lane << 2)) = acc;
}

extern "C" void kernel_launch(void* const* d_in, const int* in_sizes, int n_in,
                              void* d_out, int out_size, void* d_ws, size_t ws_size,
                              hipStream_t stream)
{
    const float* X  = (const float*)d_in[0];
    const int*   ei = (const int*)d_in[1];
    const float* W  = (const float*)d_in[2];
    const float* a  = (const float*)d_in[3];
    float* out = (float*)d_out;

    const int N_ = in_sizes[0] / 256;  // 50000
    const int E_ = in_sizes[1] / 2;    // 800000
    const int* src = ei;
    const int* tgt = ei + E_;

    // workspace layout
    float* Hf      = (float*)d_ws;                    // N*256 f
    float* asrc    = Hf      + (size_t)N_ * 256;      // N*8 f
    float* atgt    = asrc    + (size_t)N_ * HD;       // N*8 f
    float* rowmax  = atgt    + (size_t)N_ * HD;       // N*8 f
    float* sumbuf  = rowmax  + (size_t)N_ * HD;       // N*8 f (contiguous w/ rowmax)
    float* invden  = sumbuf  + (size_t)N_ * HD;       // N*8 f
    int*   deg     = (int*)(invden + (size_t)N_ * HD);// N i
    int*   rowptr  = deg     + N_;                    // N i
    int*   cursor  = rowptr  + N_;                    // N i
    int*   bsums   = cursor  + N_;                    // 256 i
    int*   csr_tgt = bsums   + 256;                   // E i

    const int nb = (N_ + 255) / 256;                  // scan blocks (196)

    // per-call zero-init
    hipMemsetAsync(rowmax, 0, (size_t)N_ * HD * 2 * sizeof(float), stream); // rowmax+sumbuf
    hipMemsetAsync(deg, 0, (size_t)N_ * sizeof(int), stream);
    hipMemsetAsync(cursor, 0, (size_t)N_ * sizeof(int), stream);

    dim3 ggrid((N_ + 63) / 64, 4);
    gemm_xwt<<<ggrid, 256, 0, stream>>>(X, W, Hf, N_);
    alpha_kernel<<<(N_ * HD + 255) / 256, 256, 0, stream>>>(Hf, a, asrc, atgt, N_ * HD);

    // CSR build
    hist_kernel<<<(E_ + 255) / 256, 256, 0, stream>>>(src, deg, E_);
    scan_block<<<nb, 256, 0, stream>>>(deg, rowptr, bsums, N_);
    scan_sums<<<1, 256, 0, stream>>>(bsums, nb);
    scan_add<<<nb, 256, 0, stream>>>(rowptr, bsums, N_);
    scatter_kernel<<<(E_ + 255) / 256, 256, 0, stream>>>(src, tgt, rowptr, cursor, csr_tgt, E_);

    // edge softmax stats
    edge_max_kernel<<<(E_ * HD + 255) / 256, 256, 0, stream>>>(
        src, tgt, asrc, atgt, (unsigned int*)rowmax, E_);
    edge_sum_kernel<<<(E_ * HD + 255) / 256, 256, 0, stream>>>(
        src, tgt, asrc, atgt, rowmax, sumbuf, E_);
    denom_kernel<<<(N_ * HD + 255) / 256, 256, 0, stream>>>(rowmax, sumbuf, deg, invden, N_);

    // atomic-free aggregation: 4 waves (nodes) per block
    node_agg<<<(N_ + 3) / 4, 256, 0, stream>>>(
        rowptr, deg, csr_tgt, asrc, atgt, rowmax, invden, Hf, out, N_);
}